// Round 3
// baseline (3687.815 us; speedup 1.0000x reference)
//
#include <hip/hip_runtime.h>

// GRU: T=1024 B=64 D=256 H=512 O=256.
// Round 5: 1-wave workgroups. Each WG = one 64-lane wave owning (16 batch
// rows x 16 h-cols); it computes ALL THREE gates for its tile (3 N-tiles
// share each A-fragment; C-layouts of the 3 accumulators are lane-identical),
// so the gate nonlinearity is pure per-lane register math. This deletes every
// __syncthreads, the lds_hx pre-activation exchange, h_out staging, and the
// producer-wave specialization of rounds 2-4 -- the structures whose barrier
// coupling of divergent wave paths was the protocol-independent ~7000cyc/step
// floor (proven by R1 vs R2: 3x different coherence RT, identical time).
// Exchange protocol (sentinel self-validating hs + XCD-consensus fast/slow
// sc0 vs sc0sc1) is carried over unchanged from the proven round-4 kernel.
// Bh lives in 192 VGPRs; Bx in LDS; xa loads + x-MFMAs hide under the poll
// via counted vmcnt. All loop-body vmem is inline asm => our waitcnts are
// exact (no compiler-counter interference).

#define T_ 1024
#define B_ 64
#define D_ 256
#define H_ 512
#define G_ 1536
#define O_ 256

#define SENT32 0x7FC07FC0u   // bf16 NaN pair: unreachable from f2b(finite)

typedef __attribute__((ext_vector_type(8))) short short8;
typedef __attribute__((ext_vector_type(4))) short short4v;
typedef __attribute__((ext_vector_type(4))) float float4v;
typedef __attribute__((ext_vector_type(4))) unsigned int uint4v;

static __device__ __forceinline__ unsigned short f2b(float f) {
  unsigned u = __builtin_bit_cast(unsigned, f);
  u += 0x7fffu + ((u >> 16) & 1u);          // RNE (finite inputs)
  return (unsigned short)(u >> 16);
}

// ---------------------------------------------------------------- prep ------
__global__ __launch_bounds__(256) void prep_kernel(
    const float* __restrict__ x, const float* __restrict__ Wi,
    const float* __restrict__ Wh, const float* __restrict__ Wo,
    unsigned short* __restrict__ xb, unsigned short* __restrict__ WhT,
    unsigned short* __restrict__ WiT, unsigned short* __restrict__ WoT,
    unsigned short* __restrict__ hs, unsigned* __restrict__ xccbuf)
{
  const size_t NX4 = (size_t)T_ * B_ * D_ / 4;   // float4 -> 4 bf16
  const size_t NWH = (size_t)G_ * H_;
  const size_t NWI = (size_t)G_ * D_;
  const size_t NWO = (size_t)O_ * H_;
  const size_t NH8 = (size_t)T_ * B_ * H_ / 8;   // uint4 sentinel chunks
  const size_t NXC = 256;
  const size_t NTOT = NX4 + NWH + NWI + NWO + NH8 + NXC;
  size_t i = (size_t)blockIdx.x * blockDim.x + threadIdx.x;
  const size_t stride = (size_t)gridDim.x * blockDim.x;
  for (; i < NTOT; i += stride) {
    if (i < NX4) {
      float4v f = ((const float4v*)x)[i];
      short4v o;
      o[0] = (short)f2b(f[0]); o[1] = (short)f2b(f[1]);
      o[2] = (short)f2b(f[2]); o[3] = (short)f2b(f[3]);
      ((short4v*)xb)[i] = o;
      continue;
    }
    size_t j = i - NX4;
    if (j < NWH) { size_t g = j >> 9, k = j & 511; WhT[j] = f2b(Wh[k * G_ + g]); continue; }
    j -= NWH;
    if (j < NWI) { size_t g = j >> 8, k = j & 255; WiT[j] = f2b(Wi[k * G_ + g]); continue; }
    j -= NWI;
    if (j < NWO) { size_t o = j >> 9, k = j & 511; WoT[j] = f2b(Wo[k * O_ + o]); continue; }
    j -= NWO;
    if (j < NH8) {
      uint4v sv = {0x7FC07FC0u, 0x7FC07FC0u, 0x7FC07FC0u, 0x7FC07FC0u};
      ((uint4v*)hs)[j] = sv;
      continue;
    }
    j -= NH8;
    xccbuf[j] = 0u;
  }
}

// ---------------------------------------------------------------- scan ------
// 256 WGs x 64 thr launched; active iff (wg&7)<4 -> 128 active 1-wave WGs.
// group = wg&7 (16 rows), slice = wg>>3 (16 h-cols). Under round-robin XCD
// dispatch all 32 WGs of a group share one XCD (one shared L2).
#define GLOAD16(FLAGS)                                                        \
  _Pragma("unroll")                                                           \
  for (int j = 0; j < 16; ++j)                                                \
    asm volatile("global_load_dwordx4 %0, %1, off " FLAGS                     \
                 : "=v"(v[j]) : "v"(src8 + j * 64 + lane));

#define FENCE_V16()                                                           \
  asm volatile("s_waitcnt vmcnt(0)"                                           \
               : "+v"(v[0]), "+v"(v[1]), "+v"(v[2]), "+v"(v[3]),              \
                 "+v"(v[4]), "+v"(v[5]), "+v"(v[6]), "+v"(v[7]),              \
                 "+v"(v[8]), "+v"(v[9]), "+v"(v[10]), "+v"(v[11]),            \
                 "+v"(v[12]), "+v"(v[13]), "+v"(v[14]), "+v"(v[15])           \
               :: "memory");                                                  \
  __builtin_amdgcn_sched_barrier(0);

#define CHECK_V16(BAD)                                                        \
  BAD = 0u;                                                                   \
  _Pragma("unroll")                                                           \
  for (int j = 0; j < 16; ++j) {                                              \
    uint4v u = __builtin_bit_cast(uint4v, v[j]);                              \
    BAD |= (unsigned)((u[0] == SENT32) | (u[1] == SENT32) |                   \
                      (u[2] == SENT32) | (u[3] == SENT32));                   \
  }

__global__ __launch_bounds__(64, 1) void scan_kernel(
    const unsigned short* __restrict__ xb,
    const unsigned short* __restrict__ WhT,
    const unsigned short* __restrict__ WiT,
    unsigned short* __restrict__ hs,
    const float* __restrict__ bi,
    const float* __restrict__ bhn,
    const float* __restrict__ h0,
    unsigned* __restrict__ xccbuf)
{
  const int wg = blockIdx.x;
  const int group = wg & 7;
  if (group >= 4) return;                     // 128 active WGs on XCDs 0..3
  const int slice = wg >> 3;                  // 0..31
  const int lane = threadIdx.x;               // one wave
  const int m = lane & 15;
  const int quad = lane >> 4;
  const int row0 = group * 16;
  const int jb = slice * 16;
  const int jcol = jb + m;

  __shared__ unsigned short hT[16 * 512];     // h tile, XOR-swizzled 16B blocks
  __shared__ unsigned short BxL[24 * 512];    // Wi fragments (3 gates x 8 k)
  __shared__ unsigned short h_lds[16 * 16];   // bounce for store transpose

  // Bh fragments in VGPRs: 3 gates x 16 K-steps
  short8 Bh[48];
#pragma unroll
  for (int g = 0; g < 3; ++g) {
    const unsigned short* p = WhT + (size_t)(g * 512 + jcol) * H_ + quad * 8;
#pragma unroll
    for (int k = 0; k < 16; ++k) Bh[g * 16 + k] = *(const short8*)(p + k * 32);
  }
  // Bx fragments staged to LDS (read each step off the critical path)
#pragma unroll
  for (int g = 0; g < 3; ++g) {
    const unsigned short* q = WiT + (size_t)(g * 512 + jcol) * D_ + quad * 8;
#pragma unroll
    for (int k = 0; k < 8; ++k)
      *(short8*)&BxL[(g * 8 + k) * 512 + lane * 8] = *(const short8*)(q + k * 32);
  }

  const float bi_r = bi[jcol];
  const float bi_z = bi[512 + jcol];
  const float bi_n = bi[1024 + jcol];
  const float bhn_c = bhn[jcol];
  float hold[4];
#pragma unroll
  for (int i = 0; i < 4; ++i)
    hold[i] = h0[(size_t)(row0 + quad * 4 + i) * H_ + jcol];

  // preamble: h0 -> hT (bf16, swizzled)
  for (int c = lane; c < 1024; c += 64) {
    const int r = c >> 6, blk = c & 63;
    const float* hp = h0 + (size_t)(row0 + r) * H_ + blk * 8;
    short8 o;
#pragma unroll
    for (int j = 0; j < 8; ++j) o[j] = (short)f2b(hp[j]);
    *(short8*)&hT[r * 512 + ((blk ^ (r & 7))) * 8] = o;
  }

  // ---- one-time XCD-homogeneity consensus (per group; identical verdicts) --
  bool fast;
  {
    unsigned xcc;
    asm("s_getreg_b32 %0, hwreg(HW_REG_XCC_ID)" : "=s"(xcc));
    if (lane == 0) {
      unsigned tok = xcc + 1u;
      unsigned* slot = xccbuf + wg;
      asm volatile("global_store_dword %0, %1, off sc0 sc1"
                   :: "v"(slot), "v"(tok) : "memory");
    }
    unsigned val = 0xffffffffu;
    if (lane < 32) {
      const unsigned* p = xccbuf + group + 8 * lane;   // the 32 group members
      do {
        asm volatile("global_load_dword %0, %1, off sc0 sc1\n\t"
                     "s_waitcnt vmcnt(0)" : "=&v"(val) : "v"(p));
      } while (val == 0u);
    }
    unsigned ref = __shfl(val, 0, 64);
    bool ok = (lane < 32) ? (val == ref) : true;
    fast = (__ballot(ok) == ~0ull);
  }

  // accx for t=0 (BxL visible to our own wave after lgkmcnt)
  asm volatile("s_waitcnt lgkmcnt(0)" ::: "memory");
  float4v axr = {0.f,0.f,0.f,0.f}, axz = {0.f,0.f,0.f,0.f}, axn = {0.f,0.f,0.f,0.f};
  {
    const unsigned short* xp = xb + ((size_t)0 * B_ + row0 + m) * D_ + quad * 8;
#pragma unroll
    for (int k = 0; k < 8; ++k) {
      short8 a = *(const short8*)(xp + k * 32);
      axr = __builtin_amdgcn_mfma_f32_16x16x32_bf16(a, *(const short8*)&BxL[(0 * 8 + k) * 512 + lane * 8], axr, 0, 0, 0);
      axz = __builtin_amdgcn_mfma_f32_16x16x32_bf16(a, *(const short8*)&BxL[(1 * 8 + k) * 512 + lane * 8], axz, 0, 0, 0);
      axn = __builtin_amdgcn_mfma_f32_16x16x32_bf16(a, *(const short8*)&BxL[(2 * 8 + k) * 512 + lane * 8], axn, 0, 0, 0);
    }
  }
  // zero both counters so in-loop counted waits are exact
  asm volatile("s_waitcnt vmcnt(0) lgkmcnt(0)" ::: "memory");

  for (int t = 0; t < T_; ++t) {
    // A: issue xa loads for t+1 (deepest in flight), then h-MFMAs from hT
    short8 xa[8];
    if (t < T_ - 1) {
      const unsigned short* xp = xb + ((size_t)(t + 1) * B_ + row0 + m) * D_ + quad * 8;
#pragma unroll
      for (int k = 0; k < 8; ++k)
        asm volatile("global_load_dwordx4 %0, %1, off"
                     : "=v"(xa[k]) : "v"(xp + k * 32));
    }
    float4v hr0 = {0.f,0.f,0.f,0.f}, hr1 = {0.f,0.f,0.f,0.f};
    float4v hz0 = {0.f,0.f,0.f,0.f}, hz1 = {0.f,0.f,0.f,0.f};
    float4v hn0 = {0.f,0.f,0.f,0.f}, hn1 = {0.f,0.f,0.f,0.f};
#pragma unroll
    for (int k = 0; k < 16; k += 2) {
      const int blk0 = (k * 4 + quad) ^ (m & 7);
      short8 a0 = *(const short8*)&hT[m * 512 + blk0 * 8];
      hr0 = __builtin_amdgcn_mfma_f32_16x16x32_bf16(a0, Bh[k],      hr0, 0, 0, 0);
      hz0 = __builtin_amdgcn_mfma_f32_16x16x32_bf16(a0, Bh[16 + k], hz0, 0, 0, 0);
      hn0 = __builtin_amdgcn_mfma_f32_16x16x32_bf16(a0, Bh[32 + k], hn0, 0, 0, 0);
      const int blk1 = ((k + 1) * 4 + quad) ^ (m & 7);
      short8 a1 = *(const short8*)&hT[m * 512 + blk1 * 8];
      hr1 = __builtin_amdgcn_mfma_f32_16x16x32_bf16(a1, Bh[k + 1],  hr1, 0, 0, 0);
      hz1 = __builtin_amdgcn_mfma_f32_16x16x32_bf16(a1, Bh[17 + k], hz1, 0, 0, 0);
      hn1 = __builtin_amdgcn_mfma_f32_16x16x32_bf16(a1, Bh[33 + k], hn1, 0, 0, 0);
    }
    // B: gates, pure per-lane register math (C-layouts of all accs coincide)
#pragma unroll
    for (int i = 0; i < 4; ++i) {
      const float pr = hr0[i] + hr1[i] + axr[i] + bi_r;
      const float pz = hz0[i] + hz1[i] + axz[i] + bi_z;
      const float rg = 1.f / (1.f + __expf(-pr));
      const float zg = 1.f / (1.f + __expf(-pz));
      const float an = axn[i] + bi_n + rg * (hn0[i] + hn1[i] + bhn_c);
      const float e2 = __expf(2.f * an);          // branch-free tanh
      const float ng = 1.f - 2.f / (e2 + 1.f);
      const float hn = (1.f - zg) * ng + zg * hold[i];
      hold[i] = hn;
      h_lds[(quad * 4 + i) * 16 + m] = f2b(hn);
    }
    // C: bounce-transpose (single-wave: lgkmcnt(0) is the only sync needed)
    asm volatile("s_waitcnt lgkmcnt(0)" ::: "memory");
    if (lane < 32) {
      const int r = lane >> 1, half = lane & 1;
      short8 hv = *(const short8*)&h_lds[r * 16 + half * 8];
      unsigned short* dst = hs + ((size_t)t * B_ + row0 + r) * H_ + jb + half * 8;
      if (fast)
        asm volatile("global_store_dwordx4 %0, %1, off sc0"
                     :: "v"(dst), "v"(hv) : "memory");
      else
        asm volatile("global_store_dwordx4 %0, %1, off sc0 sc1"
                     :: "v"(dst), "v"(hv) : "memory");
    }
    if (t == T_ - 1) break;

    // E-issue: poll loads for the group's full 16KB h tile (contiguous)
    const short8* src8 = (const short8*)(hs + ((size_t)t * B_ + row0) * H_);
    short8 v[16];
    if (fast) { GLOAD16("sc0") } else { GLOAD16("sc0 sc1") }

    // wait xa only: queue = [8 xa][1 store][16 poll] -> vmcnt(17) retires xa
    asm volatile("s_waitcnt vmcnt(17)"
                 : "+v"(xa[0]), "+v"(xa[1]), "+v"(xa[2]), "+v"(xa[3]),
                   "+v"(xa[4]), "+v"(xa[5]), "+v"(xa[6]), "+v"(xa[7])
                 :: "memory");
    __builtin_amdgcn_sched_barrier(0);
    // D: x-MFMAs for t+1 (hidden under poll flight + store visibility)
    {
      float4v nr = {0.f,0.f,0.f,0.f}, nz = {0.f,0.f,0.f,0.f}, nn = {0.f,0.f,0.f,0.f};
#pragma unroll
      for (int k = 0; k < 8; ++k) {
        nr = __builtin_amdgcn_mfma_f32_16x16x32_bf16(xa[k], *(const short8*)&BxL[(0 * 8 + k) * 512 + lane * 8], nr, 0, 0, 0);
        nz = __builtin_amdgcn_mfma_f32_16x16x32_bf16(xa[k], *(const short8*)&BxL[(1 * 8 + k) * 512 + lane * 8], nz, 0, 0, 0);
        nn = __builtin_amdgcn_mfma_f32_16x16x32_bf16(xa[k], *(const short8*)&BxL[(2 * 8 + k) * 512 + lane * 8], nn, 0, 0, 0);
      }
      axr = nr; axz = nz; axn = nn;
    }
    // detect: a chunk is ready when no dword equals the sentinel pair
    unsigned bad;
    FENCE_V16();
    CHECK_V16(bad);
    while (__any((int)bad)) {
      if (bad) {
        if (fast) { GLOAD16("sc0") } else { GLOAD16("sc0 sc1") }
      }
      FENCE_V16();
      CHECK_V16(bad);
    }
    // F: gather -> hT (swizzled); next A-reads fenced by lgkmcnt
#pragma unroll
    for (int j = 0; j < 16; ++j)
      *(short8*)&hT[j * 512 + ((lane ^ (j & 7))) * 8] = v[j];
    asm volatile("s_waitcnt lgkmcnt(0)" ::: "memory");
  }
}

// ---------------------------------------------------------------- ogemm -----
__global__ __launch_bounds__(256) void ogemm_kernel(
    const unsigned short* __restrict__ hs, const unsigned short* __restrict__ WoT,
    const float* __restrict__ bo, float* __restrict__ out)
{
  const int wv = threadIdx.x >> 6, lane = threadIdx.x & 63;
  const int m = lane & 15, quad = lane >> 4;
  const int rowbase = blockIdx.x * 64 + wv * 16;
  const unsigned short* ap = hs + (size_t)(rowbase + m) * H_ + quad * 8;
  float4v acc[16];
#pragma unroll
  for (int n = 0; n < 16; ++n) { float4v z = {0.f,0.f,0.f,0.f}; acc[n] = z; }
#pragma unroll
  for (int k = 0; k < 16; ++k) {
    short8 a = *(const short8*)(ap + k * 32);
#pragma unroll
    for (int n = 0; n < 16; ++n) {
      short8 b = *(const short8*)(WoT + (size_t)(n * 16 + m) * H_ + k * 32 + quad * 8);
      acc[n] = __builtin_amdgcn_mfma_f32_16x16x32_bf16(a, b, acc[n], 0, 0, 0);
    }
  }
#pragma unroll
  for (int n = 0; n < 16; ++n) {
    const int col = n * 16 + m;
    const float bias = bo[col];
#pragma unroll
    for (int i = 0; i < 4; ++i) {
      const int r = rowbase + quad * 4 + i;
      out[(size_t)r * O_ + col] = acc[n][i] + bias;
    }
  }
}

// ---------------------------------------------------------------- launch ----
extern "C" void kernel_launch(void* const* d_in, const int* in_sizes, int n_in,
                              void* d_out, int out_size, void* d_ws, size_t ws_size,
                              hipStream_t stream)
{
  const float* x   = (const float*)d_in[0];
  const float* Wi  = (const float*)d_in[1];
  const float* bi  = (const float*)d_in[2];
  const float* Wh  = (const float*)d_in[3];
  const float* bhn = (const float*)d_in[4];
  const float* Wo  = (const float*)d_in[5];
  const float* bo  = (const float*)d_in[6];
  const float* h0  = (const float*)d_in[7];
  float* out = (float*)d_out;

  char* ws = (char*)d_ws;
  unsigned short* xb  = (unsigned short*)ws;  ws += (size_t)T_ * B_ * D_ * 2;  // 33.5 MB
  unsigned short* WhT = (unsigned short*)ws;  ws += (size_t)G_ * H_ * 2;       // 1.5 MB
  unsigned short* WiT = (unsigned short*)ws;  ws += (size_t)G_ * D_ * 2;       // 0.75 MB
  unsigned short* WoT = (unsigned short*)ws;  ws += (size_t)O_ * H_ * 2;       // 0.25 MB
  unsigned short* hs  = (unsigned short*)ws;  ws += (size_t)T_ * B_ * H_ * 2;  // 67 MB
  unsigned* xccbuf    = (unsigned*)ws;                                          // 1 KB

  prep_kernel<<<4096, 256, 0, stream>>>(x, Wi, Wh, Wo, xb, WhT, WiT, WoT, hs, xccbuf);
  scan_kernel<<<256, 64, 0, stream>>>(xb, WhT, WiT, hs, bi, bhn, h0, xccbuf);
  ogemm_kernel<<<1024, 256, 0, stream>>>(hs, WoT, bo, out);
}